// Round 9
// baseline (172.122 us; speedup 1.0000x reference)
//
#include <hip/hip_runtime.h>
#include <cstdint>
#include <cstddef>

typedef short bf16x8 __attribute__((ext_vector_type(8)));
typedef float f32x4 __attribute__((ext_vector_type(4)));

#define EPS 1e-3f

__device__ __forceinline__ short f32_to_bf16s(float f) {
    union { float f; uint32_t u; } v; v.f = f;
    return (short)((v.u + 0x7FFFu + ((v.u >> 16) & 1u)) >> 16);
}
__device__ __forceinline__ float bf16s_to_f32(short s) {
    union { uint32_t u; float f; } v; v.u = ((uint32_t)(unsigned short)s) << 16;
    return v.f;
}

// K0: wt[kp][ci] = bf16(W[ci][kp]) (192x64); at[w][k] = bf16(A[p][v][w]) (32x96, k=p*25+v, zero-padded)
__global__ __launch_bounds__(256) void prep_kernel(const float* __restrict__ A,
                                                   const float* __restrict__ W,
                                                   unsigned short* __restrict__ wt,
                                                   unsigned short* __restrict__ at) {
    int idx = blockIdx.x * 256 + threadIdx.x;
    if (idx < 12288) {
        int kp = idx >> 6, ci = idx & 63;
        wt[idx] = (unsigned short)f32_to_bf16s(W[ci * 192 + kp]);
    } else {
        int j = idx - 12288;
        if (j < 3072) {
            int w = j / 96, k = j - w * 96;
            float val = 0.f;
            if (w < 25 && k < 75) {
                int p = k / 25, v = k - p * 25;
                val = A[(p * 25 + v) * 25 + w];
            }
            at[j] = (unsigned short)f32_to_bf16s(val);
        }
    }
}

// Mega: block = (l-chunk of 8, n), 512 threads; wave wv owns l = l0+wv end-to-end.
// LDS: smem = H [0,13056) slabH[ci][l 0..7][v] stride 204 -> in-place xw -> Ys[128][96]
//             B [13056,26112) slabB[ci][l 0..7][v] (body x, residual source, persists)
// Phase 1a is fully-coalesced float4; windows computed in-LDS with thread-private
// in-place writes (no extra barrier). Three barriers total.
__global__ __launch_bounds__(512, 4) void mega_kernel(
    const float* __restrict__ x,
    const unsigned short* __restrict__ wt,
    const unsigned short* __restrict__ at,
    const float* __restrict__ gamma, const float* __restrict__ beta,
    const float* __restrict__ mean, const float* __restrict__ var,
    float* __restrict__ out) {
    const int ch = blockIdx.x, n = blockIdx.y;
    const int l0 = ch * 8;
    const int tid = threadIdx.x;
    const int wv = tid >> 6, lane = tid & 63, q = lane >> 4, lcol = lane & 15;

    __shared__ __align__(16) short smem[26112];
    __shared__ float scs[64], shs[64];

    // b2 fragments (at, L2-resident) + BN constants
    bf16x8 b2[2][3];
    #pragma unroll
    for (int nt = 0; nt < 2; ++nt)
        #pragma unroll
        for (int s = 0; s < 3; ++s)
            b2[nt][s] = *(const bf16x8*)(at + (size_t)(nt * 16 + lcol) * 96 + 32 * s + 8 * q);
    if (tid < 64) {
        float sc = gamma[tid] * rsqrtf(var[tid] + EPS);
        scs[tid] = sc;
        shs[tid] = beta[tid] - mean[tid] * sc;
    }

    // Phase 1a: coalesced float4 staging of x elements (l0-8)*25 .. (l0+8)*25 per ci -> bf16 LDS
    {
        const float* xn = x + (size_t)n * 480000;
        const int e0 = l0 * 25 - 200;
        #pragma unroll
        for (int rep = 0; rep < 13; ++rep) {
            int i = tid + rep * 512;
            if (i < 6400) {
                int ci = i / 100, j = i - ci * 100;
                int e = e0 + 4 * j;
                float4 val = make_float4(0.f, 0.f, 0.f, 0.f);
                if (e >= 0 && e <= 7496)
                    val = *(const float4*)(xn + (size_t)ci * 7500 + e);
                short4 sv;
                sv.x = f32_to_bf16s(val.x); sv.y = f32_to_bf16s(val.y);
                sv.z = f32_to_bf16s(val.z); sv.w = f32_to_bf16s(val.w);
                int dst = (j < 50) ? (ci * 204 + 4 * j) : (13056 + ci * 204 + 4 * j - 200);
                *(short4*)&smem[dst] = sv;
            }
        }
    }
    __syncthreads();   // barrier 1: slabs ready

    // Phase 1b: running 9-window per col (ci,v); output IN-PLACE into own halo slots.
    // Slot [ci][j][v] is read/written only by the thread owning col (ci,v) -> no barrier.
    #pragma unroll 1
    for (int rep = 0; rep < 4; ++rep) {
        int cidx = tid + rep * 512;
        if (cidx < 1600) {
            int ci = cidx / 25, v = cidx - ci * 25;
            short* hp = &smem[ci * 204 + v];
            const short* bp = &smem[13056 + ci * 204 + v];
            float hv[8], bv[8];
            #pragma unroll
            for (int j = 0; j < 8; ++j) hv[j] = bf16s_to_f32(hp[j * 25]);
            #pragma unroll
            for (int j = 0; j < 8; ++j) bv[j] = bf16s_to_f32(bp[j * 25]);
            float run = hv[0] + hv[1] + hv[2] + hv[3] + hv[4] + hv[5] + hv[6] + hv[7];
            #pragma unroll
            for (int j = 0; j < 8; ++j) {
                run += bv[j];
                hp[j * 25] = f32_to_bf16s(run);
                run -= hv[j];
            }
        }
    }
    __syncthreads();   // barrier 2: xw (in H) ready for cross-thread gathers

    // b1 fragments: B[k=ci][col], col = wv*25 + nt*16 + lcol (<=206; overflow reads
    // land in slabB = finite x data; their D-columns map to w>=25, never stored)
    bf16x8 b1[2][2];
    #pragma unroll
    for (int nt = 0; nt < 2; ++nt) {
        int col = wv * 25 + nt * 16 + lcol;
        #pragma unroll
        for (int s = 0; s < 2; ++s) {
            bf16x8 f;
            #pragma unroll
            for (int j = 0; j < 8; ++j)
                f[j] = smem[(32 * s + 8 * q + j) * 204 + col];
            b1[nt][s] = f;
        }
    }
    __syncthreads();   // barrier 3: H region becomes Ys[128][96]

    // Zero own Ys rows' pad cols [75,96) (wave-private)
    #pragma unroll
    for (int i = lane; i < 336; i += 64) {
        int r = i / 21, kk = 75 + (i - r * 21);
        smem[(wv * 16 + r) * 96 + kk] = 0;
    }

    const int lg = l0 + wv;
    const size_t outrow = ((size_t)n * 64 * 300 + lg) * 25;   // + c*7500 + w

    #pragma unroll 1
    for (int g = 0; g < 4; ++g) {
        // a1 fragments for this c-group (wt, L1/L2-resident)
        bf16x8 a1[3][2];
        #pragma unroll
        for (int mt = 0; mt < 3; ++mt)
            #pragma unroll
            for (int s = 0; s < 2; ++s)
                a1[mt][s] = *(const bf16x8*)(wt + (size_t)(g * 48 + mt * 16 + lcol) * 64 + 32 * s + 8 * q);

        // GEMM1: M=48 (kp of group g), N=32 (own l, v+pad), K=64
        f32x4 acc[3][2];
        #pragma unroll
        for (int mt = 0; mt < 3; ++mt)
            #pragma unroll
            for (int nt = 0; nt < 2; ++nt) acc[mt][nt] = (f32x4){0.f, 0.f, 0.f, 0.f};
        #pragma unroll
        for (int s = 0; s < 2; ++s)
            #pragma unroll
            for (int mt = 0; mt < 3; ++mt) {
                bf16x8 av = a1[mt][s];
                #pragma unroll
                for (int nt = 0; nt < 2; ++nt)
                    acc[mt][nt] = __builtin_amdgcn_mfma_f32_16x16x32_bf16(av, b1[nt][s], acc[mt][nt], 0, 0, 0);
            }

        // Stage D -> own Ys slab rows (wv*16+cl), col 25p+v  (wave-private)
        #pragma unroll
        for (int mt = 0; mt < 3; ++mt)
            #pragma unroll
            for (int nt = 0; nt < 2; ++nt) {
                int v = nt * 16 + lcol;
                if (v < 25) {
                    #pragma unroll
                    for (int r = 0; r < 4; ++r) {
                        int kpl = mt * 16 + 4 * q + r;
                        int cl = kpl / 3, p = kpl - 3 * cl;
                        smem[(wv * 16 + cl) * 96 + 25 * p + v] = f32_to_bf16s(acc[mt][nt][r]);
                    }
                }
            }

        // GEMM2: M=16 (cl), N=32 (w), K=96 — reads own slab
        f32x4 c0 = {0.f, 0.f, 0.f, 0.f}, c1 = {0.f, 0.f, 0.f, 0.f};
        #pragma unroll
        for (int s = 0; s < 3; ++s) {
            bf16x8 a2 = *(const bf16x8*)&smem[(wv * 16 + lcol) * 96 + 32 * s + 8 * q];
            c0 = __builtin_amdgcn_mfma_f32_16x16x32_bf16(a2, b2[0][s], c0, 0, 0, 0);
            c1 = __builtin_amdgcn_mfma_f32_16x16x32_bf16(a2, b2[1][s], c1, 0, 0, 0);
        }

        // Epilogue: BN + ReLU + residual (from slabB in LDS) + ReLU
        if (lg < 300) {
            #pragma unroll
            for (int nt = 0; nt < 2; ++nt) {
                int w = nt * 16 + lcol;
                if (w < 25) {
                    f32x4 cc = nt ? c1 : c0;
                    #pragma unroll
                    for (int r = 0; r < 4; ++r) {
                        int c = g * 16 + 4 * q + r;
                        float res = bf16s_to_f32(smem[13056 + c * 204 + wv * 25 + w]);
                        float o = fmaxf(cc[r] * scs[c] + shs[c], 0.f);
                        out[outrow + (size_t)c * 7500 + w] = fmaxf(o + res, 0.f);
                    }
                }
            }
        }
    }
}

extern "C" void kernel_launch(void* const* d_in, const int* in_sizes, int n_in,
                              void* d_out, int out_size, void* d_ws, size_t ws_size,
                              hipStream_t stream) {
    const float* x     = (const float*)d_in[0];
    const float* A     = (const float*)d_in[1];
    const float* W     = (const float*)d_in[2];
    const float* gamma = (const float*)d_in[3];
    const float* beta  = (const float*)d_in[4];
    const float* mean  = (const float*)d_in[5];
    const float* var   = (const float*)d_in[6];
    float* out = (float*)d_out;

    char* ws = (char*)d_ws;
    unsigned short* wt = (unsigned short*)ws;               // 24,576 B
    unsigned short* at = (unsigned short*)(ws + 24576);     // 6,144 B

    prep_kernel<<<60, 256, 0, stream>>>(A, W, wt, at);
    mega_kernel<<<dim3(38, 32), 512, 0, stream>>>(x, wt, at, gamma, beta, mean, var, out);
}